// Round 6
// baseline (3210.281 us; speedup 1.0000x reference)
//
#include <hip/hip_runtime.h>
#include <hip/hip_bf16.h>
#include <stdint.h>

typedef unsigned short u16;
typedef unsigned int   u32;
typedef unsigned long long ull;
typedef __attribute__((ext_vector_type(8))) short short8;
typedef __attribute__((ext_vector_type(4))) float f32x4;
typedef __attribute__((ext_vector_type(16))) float f32x16;

#define T_OUT 36
#define NB    256
#define S_IN  96
#define DD    1024
#define HH    1024

#define OFF_HID  9437184
#define OFF_ATTN 9961472

enum { EPI_BF16 = 2, EPI_YOUT = 3, EPI_YBATCH = 4, EPI_SCX = 5, EPI_CX = 6,
       EPI_COMB2 = 7 };

__device__ __forceinline__ float b2f(u16 u) {
    return __uint_as_float(((u32)u) << 16);
}
__device__ __forceinline__ u16 f2b(float f) {
    __hip_bfloat16 h = __float2bfloat16(f);
    return __builtin_bit_cast(unsigned short, h);
}

template <int RAW>
__device__ __forceinline__ short8 ld8(const void* p, size_t eoff, bool isbf) {
    if (RAW == 0 || isbf) {
        return *(const short8*)((const u16*)p + eoff);
    } else {
        const float* f = (const float*)p + eoff;
        short8 r;
        #pragma unroll
        for (int i = 0; i < 8; ++i) r[i] = (short)f2b(f[i]);
        return r;
    }
}

// dtype detector: flag=1 -> bf16 inputs, 0 -> f32 inputs.
__global__ __launch_bounds__(256) void k_detect(const u32* __restrict__ t,
                                                int* __restrict__ flag)
{
    __shared__ int cnt[256];
    u32 w = t[threadIdx.x];
    int e = (w >> 7) & 0xFF;
    cnt[threadIdx.x] = (e >= 100 && e <= 140) ? 1 : 0;
    __syncthreads();
    for (int s = 128; s > 0; s >>= 1) {
        if (threadIdx.x < s) cnt[threadIdx.x] += cnt[threadIdx.x + s];
        __syncthreads();
    }
    if (threadIdx.x == 0) flag[0] = (cnt[0] >= 128) ? 1 : 0;
}

__global__ __launch_bounds__(256) void k_cvt16(const void* __restrict__ src,
                                               u16* __restrict__ dst, int n4,
                                               const int* __restrict__ flagp)
{
    const int i = blockIdx.x * 256 + threadIdx.x;
    if (i >= n4) return;
    if (*flagp) {
        ((ull*)dst)[i] = ((const ull*)src)[i];
    } else {
        f32x4 v = ((const f32x4*)src)[i];
        ull pk = (ull)f2b(v[0]) | ((ull)f2b(v[1]) << 16)
               | ((ull)f2b(v[2]) << 32) | ((ull)f2b(v[3]) << 48);
        ((ull*)dst)[i] = pk;
    }
}

__global__ __launch_bounds__(256) void k_cvtf(const void* __restrict__ src,
                                              float* __restrict__ dst, int n,
                                              const int* __restrict__ flagp)
{
    const int i = blockIdx.x * 256 + threadIdx.x;
    if (i >= n) return;
    dst[i] = *flagp ? b2f(((const u16*)src)[i]) : ((const float*)src)[i];
}

// Transpose 1024x1024 sub-block: out[k][d] = in[d][col0+k], in has ldin elems/row.
__global__ __launch_bounds__(256) void k_trcvt(const void* __restrict__ in,
                                               u16* __restrict__ out,
                                               int ldin, int col0,
                                               const int* __restrict__ flagp)
{
    const bool isbf = (*flagp != 0);
    __shared__ u16 tile[64][65];
    const int bx = blockIdx.x * 64, by = blockIdx.y * 64;
    const int c = threadIdx.x & 63, r0 = threadIdx.x >> 6;
    #pragma unroll
    for (int rr = 0; rr < 16; ++rr) {
        int r = r0 * 16 + rr;
        size_t idx = (size_t)(by + r) * ldin + col0 + bx + c;
        tile[r][c] = isbf ? ((const u16*)in)[idx] : f2b(((const float*)in)[idx]);
    }
    __syncthreads();
    #pragma unroll
    for (int rr = 0; rr < 16; ++rr) {
        int r = r0 * 16 + rr;
        out[(size_t)(bx + r) * 1024 + by + c] = tile[c][r];
    }
}

// bc[d] = out2W[d,:] . out1B + out2B[d]   (1024 waves, wave-parallel dot)
__global__ __launch_bounds__(256) void k_bc(const void* __restrict__ W2,
                                            const void* __restrict__ b1,
                                            const void* __restrict__ b2,
                                            float* __restrict__ bc,
                                            const int* __restrict__ flagp)
{
    const bool isbf = (*flagp != 0);
    const int lane = threadIdx.x & 63;
    const int d = blockIdx.x * 4 + (threadIdx.x >> 6);
    float s = 0.f;
    if (isbf) {
        const u16* wr = (const u16*)W2 + (size_t)d * 1024 + lane * 16;
        const u16* bb = (const u16*)b1 + lane * 16;
        #pragma unroll
        for (int c = 0; c < 2; ++c) {
            short8 a = *(const short8*)(wr + c * 8);
            short8 v = *(const short8*)(bb + c * 8);
            #pragma unroll
            for (int e = 0; e < 8; ++e) s += b2f((u16)a[e]) * b2f((u16)v[e]);
        }
    } else {
        const float* wr = (const float*)W2 + (size_t)d * 1024 + lane * 16;
        const float* bb = (const float*)b1 + lane * 16;
        #pragma unroll
        for (int c = 0; c < 4; ++c) {
            f32x4 a = *(const f32x4*)(wr + c * 4);
            f32x4 v = *(const f32x4*)(bb + c * 4);
            s += a[0]*v[0] + a[1]*v[1] + a[2]*v[2] + a[3]*v[3];
        }
    }
    #pragma unroll
    for (int dd = 32; dd > 0; dd >>= 1) s += __shfl_xor(s, dd, 64);
    if (lane == 0) {
        float b2v = isbf ? b2f(((const u16*)b2)[d]) : ((const float*)b2)[d];
        bc[d] = s + b2v;
    }
}

// ---------------------------------------------------------------------------
// Generic GEMM: 128x128 tile, 256 threads (4 waves, each a 64x64 quadrant of
// 2x2 32x32 MFMA tiles), 1-deep global-load prefetch, stride-5 LDS row pad
// (row bank-phase cycles 8 instead of 2 -> <=4-way conflicts).
// Requires M % 128 == 0; N guarded.
// ---------------------------------------------------------------------------
template <int EPI, int RAWA, int RAWB>
__global__ __launch_bounds__(256) void k_gemm(
    const void* __restrict__ A, const void* __restrict__ B, void* __restrict__ Cp,
    int lda, int ldb, int M, int N, int K,
    const float* __restrict__ fbias, int t, int ldc,
    const int* __restrict__ flagp, size_t boff, const void* __restrict__ Xadd)
{
    const bool isbf = (*flagp != 0);
    __shared__ short8 As[128 * 5];   // 10 KB
    __shared__ short8 Bs[128 * 5];   // 10 KB

    const int tid  = threadIdx.x;
    const int lane = tid & 63;
    const int w    = tid >> 6;
    const int wr   = w >> 1, wc = w & 1;
    const int bm   = blockIdx.x * 128;
    const int bn   = blockIdx.y * 128;

    const int srow = tid >> 2;       // 0..63
    const int sg   = tid & 3;
    const int m0   = lane & 31;
    const int kq   = lane >> 5;

    f32x16 acc[2][2];
    #pragma unroll
    for (int i = 0; i < 2; ++i)
        #pragma unroll
        for (int j = 0; j < 2; ++j) acc[i][j] = (f32x16)0.0f;

    short8 av[2], bv[2];
    auto LOADG = [&](int kt) {
        const int k0 = kt << 5;
        #pragma unroll
        for (int i = 0; i < 2; ++i) {
            int r = srow + 64 * i;                 // 0..127
            av[i] = ld8<RAWA>(A, (size_t)(bm + r) * lda + k0 + sg * 8, isbf);
            int gr = bn + r;
            if (gr < N) bv[i] = ld8<RAWB>(B, boff + (size_t)gr * ldb + k0 + sg * 8, isbf);
            else        bv[i] = (short8)(short)0;
        }
    };

    const int kiter = K >> 5;
    LOADG(0);
    for (int kt = 0; kt < kiter; ++kt) {
        __syncthreads();
        #pragma unroll
        for (int i = 0; i < 2; ++i) {
            int r = srow + 64 * i;
            As[r * 5 + (sg ^ (r & 3))] = av[i];
            Bs[r * 5 + (sg ^ (r & 3))] = bv[i];
        }
        __syncthreads();
        if (kt + 1 < kiter) LOADG(kt + 1);
        #pragma unroll
        for (int ks = 0; ks < 2; ++ks) {
            const int gk = ks * 2 + kq;
            short8 af[2], bf[2];
            #pragma unroll
            for (int i = 0; i < 2; ++i) {
                int r = wr * 64 + i * 32 + m0;
                af[i] = As[r * 5 + (gk ^ (r & 3))];
            }
            #pragma unroll
            for (int j = 0; j < 2; ++j) {
                int r = wc * 64 + j * 32 + m0;
                bf[j] = Bs[r * 5 + (gk ^ (r & 3))];
            }
            #pragma unroll
            for (int i = 0; i < 2; ++i)
                #pragma unroll
                for (int j = 0; j < 2; ++j)
                    acc[i][j] = __builtin_amdgcn_mfma_f32_32x32x16_bf16(
                        af[i], bf[j], acc[i][j], 0, 0, 0);
        }
    }

    #pragma unroll
    for (int i = 0; i < 2; ++i) {
        #pragma unroll
        for (int j = 0; j < 2; ++j) {
            #pragma unroll
            for (int reg = 0; reg < 16; ++reg) {
                int row = (reg & 3) + 8 * (reg >> 2) + 4 * kq;
                int gr = bm + wr * 64 + i * 32 + row;
                int gc = bn + wc * 64 + j * 32 + m0;
                if (gc < N) {
                    float v = acc[i][j][reg];
                    if constexpr (EPI == EPI_COMB2) {
                        size_t cidx = ((size_t)gr * T_OUT + t) * DD + gc;
                        float cx = isbf ? b2f(((const u16*)Xadd)[cidx])
                                        : ((const float*)Xadd)[cidx];
                        v += fbias[gc] + cx;
                        v = fmaxf(v, 0.0f);
                        ((u16*)Cp)[(size_t)gr * ldc + gc] = f2b(v);
                    } else if constexpr (EPI == EPI_BF16) {
                        ((u16*)Cp)[(size_t)gr * ldc + gc] = f2b(v);
                    } else if constexpr (EPI == EPI_SCX) {
                        // x-half of attn logits -> d_out attn region
                        size_t oidx = (size_t)OFF_ATTN + (size_t)gr * ldc + gc;
                        if (isbf) ((u16*)Cp)[oidx] = f2b(v);
                        else      ((float*)Cp)[oidx] = v;
                    } else if constexpr (EPI == EPI_CX) {
                        // x-half of comb -> d_out y region (row gr = b*36+t)
                        if (isbf) ((u16*)Cp)[(size_t)gr * ldc + gc] = f2b(v);
                        else      ((float*)Cp)[(size_t)gr * ldc + gc] = v;
                    } else if constexpr (EPI == EPI_YOUT) {
                        v += fbias[gc];
                        size_t oidx = (size_t)gr * (T_OUT * DD) + (size_t)t * DD + gc;
                        if (isbf) ((u16*)Cp)[oidx] = f2b(v);
                        else      ((float*)Cp)[oidx] = v;
                    } else { // EPI_YBATCH: gr = t*256+b
                        v += fbias[gc];
                        int tt = gr >> 8, bb = gr & 255;
                        size_t oidx = (size_t)bb * (T_OUT * DD) + (size_t)tt * DD + gc;
                        if (isbf) ((u16*)Cp)[oidx] = f2b(v);
                        else      ((float*)Cp)[oidx] = v;
                    }
                }
            }
        }
    }
}

// ---------------------------------------------------------------------------
// Fused GRU layer: 512 threads = FOUR 2-wave K-groups, each covering K/4=256
// (8 serial iterations) into private LDS staging (4 x 20 KB); partials
// combined via two 3-acc LDS reduction rounds (73.7 KB alias of staging).
// Tile 64 batch-rows x 32 gate-cols, grid (32, 4) J0-major (weight-panel
// XCD affinity).
// ---------------------------------------------------------------------------
template <int RAWB>
__global__ __launch_bounds__(512) void k_gruf(
    const u16* __restrict__ X, const u16* __restrict__ Hin,
    const void* __restrict__ Wih, const void* __restrict__ Whh, size_t w_eoff,
    const float* __restrict__ biF, const float* __restrict__ bhF,
    float* __restrict__ hfl, u16* __restrict__ Hout,
    u16* __restrict__ hist, int t, const int* __restrict__ flagp)
{
    const bool isbf = (*flagp != 0);
    __shared__ __align__(16) char smem[81920];   // 4 x 20 KB staging / dump

    const int tid  = threadIdx.x;
    const int g    = tid >> 7;          // K-group 0..3
    const int tid2 = tid & 127;
    short8* Xs = (short8*)(smem + g * 20480);
    short8* Hs = (short8*)(smem + g * 20480 + 4096);
    short8* Ws = (short8*)(smem + g * 20480 + 8192);
    float*  Pp = (float*)smem;

    const int lane = tid2 & 63;
    const int w    = tid2 >> 6;
    const int J0   = blockIdx.x * 32;   // gate-col tile (major)
    const int bm   = blockIdx.y * 64;   // batch-row tile (minor)
    const int m0   = lane & 31;
    const int kq   = lane >> 5;

    f32x16 acc[6];
    #pragma unroll
    for (int q = 0; q < 6; ++q) acc[q] = (f32x16)0.0f;

    const int srr = tid2 >> 2;
    const int sg  = tid2 & 3;

    short8 xv[2], hv[2], wv[6];
    auto LOAD = [&](int kt) {
        const int k0 = kt << 5;
        #pragma unroll
        for (int i = 0; i < 2; ++i) {
            int idx = i * 128 + tid2;
            int row = idx >> 2, gg = idx & 3;
            xv[i] = *(const short8*)(X   + (size_t)(bm + row) * 1024 + k0 + gg * 8);
            hv[i] = *(const short8*)(Hin + (size_t)(bm + row) * 1024 + k0 + gg * 8);
        }
        #pragma unroll
        for (int i = 0; i < 6; ++i) {
            int gate = (i < 3) ? i : i - 3;
            const void* mat = (i < 3) ? Wih : Whh;
            size_t grow = (size_t)(gate * 1024 + J0 + srr);
            wv[i] = ld8<RAWB>(mat, w_eoff + grow * 1024 + k0 + sg * 8, isbf);
        }
    };

    const int kt0 = g * 8;
    LOAD(kt0);
    for (int i = 0; i < 8; ++i) {
        __syncthreads();
        #pragma unroll
        for (int ii = 0; ii < 2; ++ii) {
            int idx = ii * 128 + tid2;
            int row = idx >> 2, gg = idx & 3;
            Xs[row * 4 + (gg ^ (row & 3))] = xv[ii];
            Hs[row * 4 + (gg ^ (row & 3))] = hv[ii];
        }
        #pragma unroll
        for (int ii = 0; ii < 6; ++ii) {
            Ws[(ii * 32 + srr) * 4 + (sg ^ (srr & 3))] = wv[ii];
        }
        __syncthreads();
        if (i < 7) LOAD(kt0 + i + 1);
        #pragma unroll
        for (int ks = 0; ks < 2; ++ks) {
            const int gk = ks * 2 + kq;
            const int r = w * 32 + m0;
            short8 ax = Xs[r * 4 + (gk ^ (r & 3))];
            short8 ah = Hs[r * 4 + (gk ^ (r & 3))];
            short8 bw[6];
            #pragma unroll
            for (int q = 0; q < 6; ++q)
                bw[q] = Ws[(q * 32 + m0) * 4 + (gk ^ (m0 & 3))];
            acc[0] = __builtin_amdgcn_mfma_f32_32x32x16_bf16(ax, bw[0], acc[0], 0, 0, 0);
            acc[1] = __builtin_amdgcn_mfma_f32_32x32x16_bf16(ax, bw[1], acc[1], 0, 0, 0);
            acc[2] = __builtin_amdgcn_mfma_f32_32x32x16_bf16(ax, bw[2], acc[2], 0, 0, 0);
            acc[3] = __builtin_amdgcn_mfma_f32_32x32x16_bf16(ah, bw[3], acc[3], 0, 0, 0);
            acc[4] = __builtin_amdgcn_mfma_f32_32x32x16_bf16(ah, bw[4], acc[4], 0, 0, 0);
            acc[5] = __builtin_amdgcn_mfma_f32_32x32x16_bf16(ah, bw[5], acc[5], 0, 0, 0);
        }
    }

    __syncthreads();   // all MFMA LDS reads done -> staging reusable as dump
    // Round A: groups 1..3 dump acc[0..2]; group 0 accumulates.
    if (g != 0) {
        #pragma unroll
        for (int q = 0; q < 3; ++q)
            #pragma unroll
            for (int reg = 0; reg < 16; ++reg)
                Pp[((g - 1) * 3 + q) * 2048 + reg * 128 + tid2] = acc[q][reg];
    }
    __syncthreads();
    if (g == 0) {
        #pragma unroll
        for (int q = 0; q < 3; ++q)
            #pragma unroll
            for (int reg = 0; reg < 16; ++reg)
                acc[q][reg] += Pp[(0 + q) * 2048 + reg * 128 + tid2]
                             + Pp[(3 + q) * 2048 + reg * 128 + tid2]
                             + Pp[(6 + q) * 2048 + reg * 128 + tid2];
    }
    __syncthreads();
    // Round B: acc[3..5]
    if (g != 0) {
        #pragma unroll
        for (int q = 0; q < 3; ++q)
            #pragma unroll
            for (int reg = 0; reg < 16; ++reg)
                Pp[((g - 1) * 3 + q) * 2048 + reg * 128 + tid2] = acc[3 + q][reg];
    }
    __syncthreads();
    if (g == 0) {
        #pragma unroll
        for (int q = 0; q < 3; ++q)
            #pragma unroll
            for (int reg = 0; reg < 16; ++reg)
                acc[3 + q][reg] += Pp[(0 + q) * 2048 + reg * 128 + tid2]
                                 + Pp[(3 + q) * 2048 + reg * 128 + tid2]
                                 + Pp[(6 + q) * 2048 + reg * 128 + tid2];

        const int jg = J0 + m0;
        const float bir = biF[jg],         bhr = bhF[jg];
        const float biz = biF[1024 + jg],  bhz = bhF[1024 + jg];
        const float bin_ = biF[2048 + jg], bhn = bhF[2048 + jg];
        #pragma unroll
        for (int reg = 0; reg < 16; ++reg) {
            int row = (reg & 3) + 8 * (reg >> 2) + 4 * kq;
            int bb = bm + w * 32 + row;
            float ir  = acc[0][reg] + bir;
            float iz  = acc[1][reg] + biz;
            float in_ = acc[2][reg] + bin_;
            float hr  = acc[3][reg] + bhr;
            float hz  = acc[4][reg] + bhz;
            float hn  = acc[5][reg] + bhn;
            float r = 1.f / (1.f + expf(-(ir + hr)));
            float z = 1.f / (1.f + expf(-(iz + hz)));
            float n = tanhf(in_ + r * hn);
            size_t hidx = (size_t)bb * 1024 + jg;
            float hold = hfl ? hfl[hidx] : b2f(Hin[hidx]);
            float hnew = (1.f - z) * n + z * hold;
            if (hfl) hfl[hidx] = hnew;
            u16 h16 = f2b(hnew);
            Hout[hidx] = h16;
            if (hist) hist[(size_t)(t * NB + bb) * HH + jg] = h16;
        }
    }
}

// ---------------------------------------------------------------------------
// Fused attention + comb step: 1024 threads/block, one block per batch elem.
// ---------------------------------------------------------------------------
__global__ __launch_bounds__(1024) void k_attn(
    const u16* __restrict__ hb1, const u16* __restrict__ attnWB,
    const float* __restrict__ attnBF, const void* __restrict__ enc,
    const u16* __restrict__ encW, const u16* __restrict__ W2t,
    const float* __restrict__ combBF, u16* __restrict__ xc,
    u16* __restrict__ wencG, void* __restrict__ d_out,
    const int* __restrict__ flagp, int t)
{
    const bool isbf = (*flagp != 0);
    __shared__ float sc[S_IN];
    __shared__ float pst[8][1024];   // 32 KB partials
    __shared__ float wencS[1024];
    const int tid  = threadIdx.x;
    const int b    = blockIdx.x;
    const int w    = tid >> 6;
    const int lane = tid & 63;

    // h operand registerized
    short8 h0v = *(const short8*)(hb1 + (size_t)b * HH + lane * 8);
    short8 h1v = *(const short8*)(hb1 + (size_t)b * HH + 512 + lane * 8);
    float hr[16];
    #pragma unroll
    for (int e = 0; e < 8; ++e) {
        hr[e]     = b2f((u16)h0v[e]);
        hr[8 + e] = b2f((u16)h1v[e]);
    }

    // scores: 16 waves x 6 scores, K=1024 (h-half of attnW)
    #pragma unroll
    for (int i = 0; i < 6; ++i) {
        const int s = w * 6 + i;
        const u16* wr = attnWB + (size_t)s * 2048 + 1024 + (size_t)lane * 8;
        float p = 0.f;
        #pragma unroll
        for (int c = 0; c < 2; ++c) {
            short8 v = *(const short8*)(wr + c * 512);
            #pragma unroll
            for (int e = 0; e < 8; ++e) p += hr[c * 8 + e] * b2f((u16)v[e]);
        }
        #pragma unroll
        for (int d = 32; d > 0; d >>= 1) p += __shfl_xor(p, d, 64);
        if (lane == 0) {
            size_t sidx = (size_t)OFF_ATTN + ((size_t)b * T_OUT + t) * S_IN + s;
            float sx = isbf ? b2f(((const u16*)d_out)[sidx])
                            : ((const float*)d_out)[sidx];
            sc[s] = p + attnBF[s] + sx;
        }
    }
    __syncthreads();

    // softmax over 96 logits, wave 0
    if (w == 0) {
        float a  = sc[lane];
        float bq = (lane < 32) ? sc[64 + lane] : -3.0e38f;
        float m = fmaxf(a, bq);
        #pragma unroll
        for (int d = 32; d > 0; d >>= 1) m = fmaxf(m, __shfl_xor(m, d, 64));
        float e0 = expf(a - m);
        float e1 = (lane < 32) ? expf(bq - m) : 0.f;
        float ss = e0 + e1;
        #pragma unroll
        for (int d = 32; d > 0; d >>= 1) ss += __shfl_xor(ss, d, 64);
        float inv = 1.f / ss;
        sc[lane] = e0 * inv;
        if (lane < 32) sc[64 + lane] = e1 * inv;
    }
    __syncthreads();

    if (tid < S_IN) {
        float a = sc[tid];
        size_t aidx = (size_t)OFF_ATTN + ((size_t)b * T_OUT + t) * S_IN + tid;
        if (isbf) ((u16*)d_out)[aidx] = f2b(a);
        else      ((float*)d_out)[aidx] = a;
    }

    const int rg = tid >> 7;
    const int hx = (tid & 127) * 8;

    if (encW) {
        // weighted encW sum -> xc directly (comb fully fused)
        float acc[8] = {0.f, 0.f, 0.f, 0.f, 0.f, 0.f, 0.f, 0.f};
        const u16* eb = encW + (size_t)b * S_IN * HH + hx;
        #pragma unroll
        for (int it = 0; it < 12; ++it) {
            const int s = it * 8 + rg;
            const float aw = sc[s];
            short8 v = *(const short8*)(eb + (size_t)s * HH);
            #pragma unroll
            for (int e = 0; e < 8; ++e) acc[e] += aw * b2f((u16)v[e]);
        }
        #pragma unroll
        for (int e = 0; e < 8; ++e) pst[rg][hx + e] = acc[e];
        __syncthreads();
        float s = pst[0][tid];
        #pragma unroll
        for (int r2 = 1; r2 < 8; ++r2) s += pst[r2][tid];
        size_t cidx = ((size_t)b * T_OUT + t) * DD + tid;
        float cx = isbf ? b2f(((const u16*)d_out)[cidx])
                        : ((const float*)d_out)[cidx];
        float v = fmaxf(cx + combBF[tid] + s, 0.f);
        xc[(size_t)b * DD + tid] = f2b(v);
        return;
    }

    // fallback: weighted enc sum -> wencS
    float acc[8] = {0.f, 0.f, 0.f, 0.f, 0.f, 0.f, 0.f, 0.f};
    if (isbf) {
        const u16* eb = (const u16*)enc + (size_t)b * S_IN * HH + hx;
        #pragma unroll
        for (int it = 0; it < 12; ++it) {
            const int s = it * 8 + rg;
            const float aw = sc[s];
            short8 v = *(const short8*)(eb + (size_t)s * HH);
            #pragma unroll
            for (int e = 0; e < 8; ++e) acc[e] += aw * b2f((u16)v[e]);
        }
    } else {
        const float* eb = (const float*)enc + (size_t)b * S_IN * HH + hx;
        #pragma unroll
        for (int it = 0; it < 12; ++it) {
            const int s = it * 8 + rg;
            const float aw = sc[s];
            f32x4 v0 = *(const f32x4*)(eb + (size_t)s * HH);
            f32x4 v1 = *(const f32x4*)(eb + (size_t)s * HH + 4);
            acc[0] += aw * v0[0]; acc[1] += aw * v0[1];
            acc[2] += aw * v0[2]; acc[3] += aw * v0[3];
            acc[4] += aw * v1[0]; acc[5] += aw * v1[1];
            acc[6] += aw * v1[2]; acc[7] += aw * v1[3];
        }
    }
    #pragma unroll
    for (int e = 0; e < 8; ++e) pst[rg][hx + e] = acc[e];
    __syncthreads();
    {
        float s = pst[0][tid];
        #pragma unroll
        for (int r2 = 1; r2 < 8; ++r2) s += pst[r2][tid];
        wencS[tid] = s;
    }
    __syncthreads();

    if (W2t) {
        // fused comb matvec fallback
        const int dq = tid & 255;
        const int kg = tid >> 8;
        const int d4 = dq * 4;
        float a0 = 0.f, a1 = 0.f, a2 = 0.f, a3 = 0.f;
        const u16* wp = W2t + (size_t)(kg * 256) * 1024 + d4;
        const float* ws = wencS + kg * 256;
        #pragma unroll 8
        for (int k = 0; k < 256; ++k) {
            float wv = ws[k];
            ull m = *(const ull*)(wp + (size_t)k * 1024);
            a0 += wv * b2f((u16)(m));
            a1 += wv * b2f((u16)(m >> 16));
            a2 += wv * b2f((u16)(m >> 32));
            a3 += wv * b2f((u16)(m >> 48));
        }
        float* P2 = &pst[0][0];
        P2[kg * 1024 + d4 + 0] = a0;
        P2[kg * 1024 + d4 + 1] = a1;
        P2[kg * 1024 + d4 + 2] = a2;
        P2[kg * 1024 + d4 + 3] = a3;
        __syncthreads();
        float s2 = P2[tid] + P2[1024 + tid] + P2[2048 + tid] + P2[3072 + tid];
        size_t cidx = ((size_t)b * T_OUT + t) * DD + tid;
        float cx = isbf ? b2f(((const u16*)d_out)[cidx])
                        : ((const float*)d_out)[cidx];
        float v = fmaxf(cx + combBF[tid] + s2, 0.f);
        xc[(size_t)b * DD + tid] = f2b(v);
    } else {
        wencG[(size_t)b * HH + tid] = f2b(wencS[tid]);
    }
}

__global__ __launch_bounds__(256) void k_init(const void* __restrict__ hid,
                                              float* __restrict__ hf,
                                              u16* __restrict__ hb,
                                              const int* __restrict__ flagp)
{
    const int i = blockIdx.x * 256 + threadIdx.x;
    float v = *flagp ? b2f(((const u16*)hid)[i]) : ((const float*)hid)[i];
    if (hf) hf[i] = v;
    hb[i] = f2b(v);
}

__global__ __launch_bounds__(256) void k_hidout(const float* __restrict__ hf,
                                                const u16* __restrict__ hb,
                                                void* __restrict__ d_out,
                                                const int* __restrict__ flagp)
{
    const int i = blockIdx.x * 256 + threadIdx.x;
    float v = hf ? hf[i] : b2f(hb[i]);
    if (*flagp) ((u16*)d_out)[OFF_HID + i] = f2b(v);
    else        ((float*)d_out)[OFF_HID + i] = v;
}

// ---------------------------------------------------------------------------
extern "C" void kernel_launch(void* const* d_in, const int* in_sizes, int n_in,
                              void* d_out, int out_size, void* d_ws, size_t ws_size,
                              hipStream_t stream)
{
    const void* target = d_in[0];
    const void* hidden = d_in[1];
    const void* enc    = d_in[2];
    const void* attnW  = d_in[3];
    const void* attnB  = d_in[4];
    const void* combW  = d_in[5];
    const void* combB  = d_in[6];
    const void* Wih    = d_in[7];
    const void* Whh    = d_in[8];
    const void* bih    = d_in[9];
    const void* bhh    = d_in[10];
    const void* out1W  = d_in[11];
    const void* out1B  = d_in[12];
    const void* out2W  = d_in[13];
    const void* out2B  = d_in[14];

    char* ws = (char*)d_ws;
    size_t off = 0;
    #define WSALLOC(name, type, bytes) type* name = (type*)(ws + off); off += (((size_t)(bytes)) + 255) & ~(size_t)255;
    WSALLOC(flag,   int,   256)
    WSALLOC(xcat,   u16,   256*2048*2)        // wenc fallback buffer
    WSALLOC(xc,     u16,   256*1024*2)
    WSALLOC(hbq,    u16,   2*2*256*1024*2)    // ping-pong x 2 layers
    WSALLOC(Wc,     u16,   1024*1024*2)
    WSALLOC(attnWB, u16,   96*2048*2)
    WSALLOC(attnBF, float, 128*4)
    WSALLOC(combBF, float, 1024*4)
    WSALLOC(bihF,   float, 2*3072*4)
    WSALLOC(bhhF,   float, 2*3072*4)
    WSALLOC(bc,     float, 1024*4)
    WSALLOC(W1t,    u16,   1024*1024*2)
    size_t off_nohf = off;
    WSALLOC(hf,     float, 2*256*1024*4)
    size_t off_core = off;                    // ~10.6 MB
    WSALLOC(WihB,   u16,   2*3072*1024*2)     // 12.6 MB
    WSALLOC(WhhB,   u16,   2*3072*1024*2)     // 12.6 MB
    WSALLOC(combW2t,u16,   1024*2048*2)       // 4.2 MB slot; uses first 2 MB
    size_t off_big = off;                     // ~40 MB
    WSALLOC(Hist,   u16,   36*256*1024*2)     // 18.9 MB
    size_t off_hist = off;                    // ~59 MB
    WSALLOC(encW,   u16,   256*96*1024*2)     // 50.3 MB  (enc @ combW_wenc^T)
    size_t off_encw = off;                    // ~109 MB
    #undef WSALLOC
    (void)off_nohf;

    const bool useHf   = (ws_size >= off_core);
    const bool BIG     = (ws_size >= off_big);
    const bool useHist = (ws_size >= off_hist);
    const bool useEncW = (ws_size >= off_encw);
    if (!useHf) hf = nullptr;

    // Host-side dtype detect via byte sizes (authoritative when they match).
    int hostbf = -1;
    if (in_sizes) {
        long long tb = (long long)in_sizes[0];
        const long long n_t = (long long)NB * T_OUT * DD;
        if (tb == n_t * 2) hostbf = 1;
        else if (tb == n_t * 4) hostbf = 0;
    }
    const bool RAWOK = (hostbf == 1);   // bf16 inputs: raw layouts match u16

    k_detect<<<1, 256, 0, stream>>>((const u32*)target, flag);
    k_init<<<2048, 256, 0, stream>>>(hidden, hf, hbq, flag);

    const u16* attnWx = (const u16*)attnW;
    if (!RAWOK) {
        k_cvt16<<<192, 256, 0, stream>>>(attnW, attnWB, 96*2048/4, flag);
        attnWx = attnWB;
    }
    k_cvtf<<<1, 256, 0, stream>>>(attnB, attnBF, 96, flag);
    k_cvtf<<<4, 256, 0, stream>>>(combB, combBF, 1024, flag);
    k_cvtf<<<24, 256, 0, stream>>>(bih, bihF, 6144, flag);
    k_cvtf<<<24, 256, 0, stream>>>(bhh, bhhF, 6144, flag);
    k_trcvt<<<dim3(16, 16), 256, 0, stream>>>(out1W, W1t, 1024, 0, flag);
    if (BIG && !useEncW) {
        k_trcvt<<<dim3(16, 16), 256, 0, stream>>>(combW, combW2t, 2048, 1024, flag);
    }

    // Wc = out2W @ out1W ; bc = out2W @ b1 + b2
    if (RAWOK) {
        k_gemm<EPI_BF16, 0, 0><<<dim3(8, 8, 1), 256, 0, stream>>>(
            out2W, W1t, Wc, 1024, 1024, 1024, 1024, 1024, nullptr, 0, 1024,
            flag, 0, nullptr);
    } else if (BIG) {
        u16* out2Wb = WihB;   // temp alias, consumed before WihB is filled
        k_cvt16<<<1024, 256, 0, stream>>>(out2W, out2Wb, 1024*1024/4, flag);
        k_gemm<EPI_BF16, 0, 0><<<dim3(8, 8, 1), 256, 0, stream>>>(
            out2Wb, W1t, Wc, 1024, 1024, 1024, 1024, 1024, nullptr, 0, 1024,
            flag, 0, nullptr);
    } else {
        k_gemm<EPI_BF16, 1, 0><<<dim3(8, 8, 1), 256, 0, stream>>>(
            out2W, W1t, Wc, 1024, 1024, 1024, 1024, 1024, nullptr, 0, 1024,
            flag, 0, nullptr);
    }
    k_bc<<<256, 256, 0, stream>>>(out2W, out1B, out2B, bc, flag);

    // GRU weight pointers
    const void* WihP = Wih;
    const void* WhhP = Whh;
    bool gru_u16 = RAWOK;
    if (!RAWOK && BIG) {
        k_cvt16<<<6144, 256, 0, stream>>>(Wih, WihB, 2*3072*1024/4, flag);
        k_cvt16<<<6144, 256, 0, stream>>>(Whh, WhhB, 2*3072*1024/4, flag);
        WihP = WihB; WhhP = WhhB; gru_u16 = true;
    }

    // Pre-scan hoists:
    //   combX = target @ combW_x^T  -> d_out y region
    //   scX   = target @ attnW_x^T  -> d_out attn region
    //   encW  = enc    @ combW_w^T  -> workspace (comb fusion operand)
    k_gemm<EPI_CX, 1, 1><<<dim3(72, 8, 1), 256, 0, stream>>>(
        target, combW, d_out, 1024, 2048, 9216, 1024, 1024, nullptr, 0, 1024,
        flag, 0, nullptr);
    k_gemm<EPI_SCX, 1, 1><<<dim3(72, 1, 1), 256, 0, stream>>>(
        target, attnW, d_out, 1024, 2048, 9216, 96, 1024, nullptr, 0, 96,
        flag, 0, nullptr);
    if (useEncW) {
        k_gemm<EPI_BF16, 1, 1><<<dim3(192, 8, 1), 256, 0, stream>>>(
            enc, combW, encW, 1024, 2048, 24576, 1024, 1024, nullptr, 0, 1024,
            flag, 1024, nullptr);
    }

    const size_t L1 = 3072ull * 1024ull;
    const int BUF = 2 * 256 * 1024;
    for (int t = 0; t < T_OUT; ++t) {
        u16* bi = hbq + (t & 1) * BUF;
        u16* bo = hbq + ((t + 1) & 1) * BUF;
        k_attn<<<256, 1024, 0, stream>>>(bi + 262144, attnWx, attnBF, enc,
                                         useEncW ? encW : nullptr,
                                         (BIG && !useEncW) ? combW2t : nullptr,
                                         combBF, xc, xcat, d_out, flag, t);
        if (!BIG && !useEncW) {
            // fallback: comb wenc-half as GEMM (A = dense wenc in xcat)
            k_gemm<EPI_COMB2, 0, 1><<<dim3(2, 8, 1), 256, 0, stream>>>(
                xcat, combW, xc, 1024, 2048, 256, 1024, 1024, combBF, t, 1024,
                flag, 1024, d_out);
        }
        if (gru_u16) {
            k_gruf<0><<<dim3(32, 4), 512, 0, stream>>>(
                xc, bi, WihP, WhhP, 0, bihF, bhhF, hf, bo, nullptr, t, flag);
            k_gruf<0><<<dim3(32, 4), 512, 0, stream>>>(
                bo, bi + 262144, WihP, WhhP, L1, bihF + 3072, bhhF + 3072,
                hf ? hf + 262144 : nullptr, bo + 262144,
                useHist ? Hist : nullptr, t, flag);
        } else {
            k_gruf<1><<<dim3(32, 4), 512, 0, stream>>>(
                xc, bi, Wih, Whh, 0, bihF, bhhF, hf, bo, nullptr, t, flag);
            k_gruf<1><<<dim3(32, 4), 512, 0, stream>>>(
                bo, bi + 262144, Wih, Whh, L1, bihF + 3072, bhhF + 3072,
                hf ? hf + 262144 : nullptr, bo + 262144,
                useHist ? Hist : nullptr, t, flag);
        }
        if (!useHist) {
            k_gemm<EPI_YOUT, 0, 0><<<dim3(2, 8, 1), 256, 0, stream>>>(
                bo + 262144, Wc, d_out, 1024, 1024, 256, 1024, 1024, bc, t, 1024,
                flag, 0, nullptr);
        }
    }

    if (useHist) {
        k_gemm<EPI_YBATCH, 0, 0><<<dim3(72, 8, 1), 256, 0, stream>>>(
            Hist, Wc, d_out, 1024, 1024, 9216, 1024, 1024, bc, 0, 1024,
            flag, 0, nullptr);
    }
    k_hidout<<<2048, 256, 0, stream>>>(hf, hbq, d_out, flag);
}

// Round 7
// 2948.794 us; speedup vs baseline: 1.0887x; 1.0887x over previous
//
#include <hip/hip_runtime.h>
#include <hip/hip_bf16.h>
#include <stdint.h>

typedef unsigned short u16;
typedef unsigned int   u32;
typedef unsigned long long ull;
typedef __attribute__((ext_vector_type(8))) short short8;
typedef __attribute__((ext_vector_type(4))) float f32x4;
typedef __attribute__((ext_vector_type(16))) float f32x16;

#define T_OUT 36
#define NB    256
#define S_IN  96
#define DD    1024
#define HH    1024

#define OFF_HID  9437184
#define OFF_ATTN 9961472

enum { EPI_BF16 = 2, EPI_YOUT = 3, EPI_YBATCH = 4, EPI_SCX = 5, EPI_CX = 6,
       EPI_COMB2 = 7 };

__device__ __forceinline__ float b2f(u16 u) {
    return __uint_as_float(((u32)u) << 16);
}
__device__ __forceinline__ u16 f2b(float f) {
    __hip_bfloat16 h = __float2bfloat16(f);
    return __builtin_bit_cast(unsigned short, h);
}

template <int RAW>
__device__ __forceinline__ short8 ld8(const void* p, size_t eoff, bool isbf) {
    if (RAW == 0 || isbf) {
        return *(const short8*)((const u16*)p + eoff);
    } else {
        const float* f = (const float*)p + eoff;
        short8 r;
        #pragma unroll
        for (int i = 0; i < 8; ++i) r[i] = (short)f2b(f[i]);
        return r;
    }
}

// dtype detector: flag=1 -> bf16 inputs, 0 -> f32 inputs.
__global__ __launch_bounds__(256) void k_detect(const u32* __restrict__ t,
                                                int* __restrict__ flag)
{
    __shared__ int cnt[256];
    u32 w = t[threadIdx.x];
    int e = (w >> 7) & 0xFF;
    cnt[threadIdx.x] = (e >= 100 && e <= 140) ? 1 : 0;
    __syncthreads();
    for (int s = 128; s > 0; s >>= 1) {
        if (threadIdx.x < s) cnt[threadIdx.x] += cnt[threadIdx.x + s];
        __syncthreads();
    }
    if (threadIdx.x == 0) flag[0] = (cnt[0] >= 128) ? 1 : 0;
}

__global__ __launch_bounds__(256) void k_cvt16(const void* __restrict__ src,
                                               u16* __restrict__ dst, int n4,
                                               const int* __restrict__ flagp)
{
    const int i = blockIdx.x * 256 + threadIdx.x;
    if (i >= n4) return;
    if (*flagp) {
        ((ull*)dst)[i] = ((const ull*)src)[i];
    } else {
        f32x4 v = ((const f32x4*)src)[i];
        ull pk = (ull)f2b(v[0]) | ((ull)f2b(v[1]) << 16)
               | ((ull)f2b(v[2]) << 32) | ((ull)f2b(v[3]) << 48);
        ((ull*)dst)[i] = pk;
    }
}

__global__ __launch_bounds__(256) void k_cvtf(const void* __restrict__ src,
                                              float* __restrict__ dst, int n,
                                              const int* __restrict__ flagp)
{
    const int i = blockIdx.x * 256 + threadIdx.x;
    if (i >= n) return;
    dst[i] = *flagp ? b2f(((const u16*)src)[i]) : ((const float*)src)[i];
}

// Transpose 1024x1024 sub-block: out[k][d] = in[d][col0+k], in has ldin elems/row.
__global__ __launch_bounds__(256) void k_trcvt(const void* __restrict__ in,
                                               u16* __restrict__ out,
                                               int ldin, int col0,
                                               const int* __restrict__ flagp)
{
    const bool isbf = (*flagp != 0);
    __shared__ u16 tile[64][65];
    const int bx = blockIdx.x * 64, by = blockIdx.y * 64;
    const int c = threadIdx.x & 63, r0 = threadIdx.x >> 6;
    #pragma unroll
    for (int rr = 0; rr < 16; ++rr) {
        int r = r0 * 16 + rr;
        size_t idx = (size_t)(by + r) * ldin + col0 + bx + c;
        tile[r][c] = isbf ? ((const u16*)in)[idx] : f2b(((const float*)in)[idx]);
    }
    __syncthreads();
    #pragma unroll
    for (int rr = 0; rr < 16; ++rr) {
        int r = r0 * 16 + rr;
        out[(size_t)(bx + r) * 1024 + by + c] = tile[c][r];
    }
}

// bc[d] = out2W[d,:] . out1B + out2B[d]
__global__ __launch_bounds__(256) void k_bc(const void* __restrict__ W2,
                                            const void* __restrict__ b1,
                                            const void* __restrict__ b2,
                                            float* __restrict__ bc,
                                            const int* __restrict__ flagp)
{
    const bool isbf = (*flagp != 0);
    const int lane = threadIdx.x & 63;
    const int d = blockIdx.x * 4 + (threadIdx.x >> 6);
    float s = 0.f;
    if (isbf) {
        const u16* wr = (const u16*)W2 + (size_t)d * 1024 + lane * 16;
        const u16* bb = (const u16*)b1 + lane * 16;
        #pragma unroll
        for (int c = 0; c < 2; ++c) {
            short8 a = *(const short8*)(wr + c * 8);
            short8 v = *(const short8*)(bb + c * 8);
            #pragma unroll
            for (int e = 0; e < 8; ++e) s += b2f((u16)a[e]) * b2f((u16)v[e]);
        }
    } else {
        const float* wr = (const float*)W2 + (size_t)d * 1024 + lane * 16;
        const float* bb = (const float*)b1 + lane * 16;
        #pragma unroll
        for (int c = 0; c < 4; ++c) {
            f32x4 a = *(const f32x4*)(wr + c * 4);
            f32x4 v = *(const f32x4*)(bb + c * 4);
            s += a[0]*v[0] + a[1]*v[1] + a[2]*v[2] + a[3]*v[3];
        }
    }
    #pragma unroll
    for (int dd = 32; dd > 0; dd >>= 1) s += __shfl_xor(s, dd, 64);
    if (lane == 0) {
        float b2v = isbf ? b2f(((const u16*)b2)[d]) : ((const float*)b2)[d];
        bc[d] = s + b2v;
    }
}

// ---------------------------------------------------------------------------
// Generic GEMM: 128x128 tile, 256 threads (4 waves, 64x64 quadrants of
// 2x2 32x32 MFMA), 1-deep global-load prefetch. M % 128 == 0; N guarded.
// ---------------------------------------------------------------------------
template <int EPI, int RAWA, int RAWB>
__global__ __launch_bounds__(256) void k_gemm(
    const void* __restrict__ A, const void* __restrict__ B, void* __restrict__ Cp,
    int lda, int ldb, int M, int N, int K,
    const float* __restrict__ fbias, int t, int ldc,
    const int* __restrict__ flagp, size_t boff, const void* __restrict__ Xadd)
{
    const bool isbf = (*flagp != 0);
    __shared__ short8 As[128 * 5];   // 10 KB
    __shared__ short8 Bs[128 * 5];   // 10 KB

    const int tid  = threadIdx.x;
    const int lane = tid & 63;
    const int w    = tid >> 6;
    const int wr   = w >> 1, wc = w & 1;
    const int bm   = blockIdx.x * 128;
    const int bn   = blockIdx.y * 128;

    const int srow = tid >> 2;       // 0..63
    const int sg   = tid & 3;
    const int m0   = lane & 31;
    const int kq   = lane >> 5;

    f32x16 acc[2][2];
    #pragma unroll
    for (int i = 0; i < 2; ++i)
        #pragma unroll
        for (int j = 0; j < 2; ++j) acc[i][j] = (f32x16)0.0f;

    short8 av[2], bv[2];
    auto LOADG = [&](int kt) {
        const int k0 = kt << 5;
        #pragma unroll
        for (int i = 0; i < 2; ++i) {
            int r = srow + 64 * i;                 // 0..127
            av[i] = ld8<RAWA>(A, (size_t)(bm + r) * lda + k0 + sg * 8, isbf);
            int gr = bn + r;
            if (gr < N) bv[i] = ld8<RAWB>(B, boff + (size_t)gr * ldb + k0 + sg * 8, isbf);
            else        bv[i] = (short8)(short)0;
        }
    };

    const int kiter = K >> 5;
    LOADG(0);
    for (int kt = 0; kt < kiter; ++kt) {
        __syncthreads();
        #pragma unroll
        for (int i = 0; i < 2; ++i) {
            int r = srow + 64 * i;
            As[r * 5 + (sg ^ (r & 3))] = av[i];
            Bs[r * 5 + (sg ^ (r & 3))] = bv[i];
        }
        __syncthreads();
        if (kt + 1 < kiter) LOADG(kt + 1);
        #pragma unroll
        for (int ks = 0; ks < 2; ++ks) {
            const int gk = ks * 2 + kq;
            short8 af[2], bf[2];
            #pragma unroll
            for (int i = 0; i < 2; ++i) {
                int r = wr * 64 + i * 32 + m0;
                af[i] = As[r * 5 + (gk ^ (r & 3))];
            }
            #pragma unroll
            for (int j = 0; j < 2; ++j) {
                int r = wc * 64 + j * 32 + m0;
                bf[j] = Bs[r * 5 + (gk ^ (r & 3))];
            }
            #pragma unroll
            for (int i = 0; i < 2; ++i)
                #pragma unroll
                for (int j = 0; j < 2; ++j)
                    acc[i][j] = __builtin_amdgcn_mfma_f32_32x32x16_bf16(
                        af[i], bf[j], acc[i][j], 0, 0, 0);
        }
    }

    #pragma unroll
    for (int i = 0; i < 2; ++i) {
        #pragma unroll
        for (int j = 0; j < 2; ++j) {
            #pragma unroll
            for (int reg = 0; reg < 16; ++reg) {
                int row = (reg & 3) + 8 * (reg >> 2) + 4 * kq;
                int gr = bm + wr * 64 + i * 32 + row;
                int gc = bn + wc * 64 + j * 32 + m0;
                if (gc < N) {
                    float v = acc[i][j][reg];
                    if constexpr (EPI == EPI_COMB2) {
                        size_t cidx = ((size_t)gr * T_OUT + t) * DD + gc;
                        float cx = isbf ? b2f(((const u16*)Xadd)[cidx])
                                        : ((const float*)Xadd)[cidx];
                        v += fbias[gc] + cx;
                        v = fmaxf(v, 0.0f);
                        ((u16*)Cp)[(size_t)gr * ldc + gc] = f2b(v);
                    } else if constexpr (EPI == EPI_BF16) {
                        ((u16*)Cp)[(size_t)gr * ldc + gc] = f2b(v);
                    } else if constexpr (EPI == EPI_SCX) {
                        size_t oidx = (size_t)OFF_ATTN + (size_t)gr * ldc + gc;
                        if (isbf) ((u16*)Cp)[oidx] = f2b(v);
                        else      ((float*)Cp)[oidx] = v;
                    } else if constexpr (EPI == EPI_CX) {
                        if (isbf) ((u16*)Cp)[(size_t)gr * ldc + gc] = f2b(v);
                        else      ((float*)Cp)[(size_t)gr * ldc + gc] = v;
                    } else if constexpr (EPI == EPI_YOUT) {
                        v += fbias[gc];
                        size_t oidx = (size_t)gr * (T_OUT * DD) + (size_t)t * DD + gc;
                        if (isbf) ((u16*)Cp)[oidx] = f2b(v);
                        else      ((float*)Cp)[oidx] = v;
                    } else { // EPI_YBATCH: gr = t*256+b
                        v += fbias[gc];
                        int tt = gr >> 8, bb = gr & 255;
                        size_t oidx = (size_t)bb * (T_OUT * DD) + (size_t)tt * DD + gc;
                        if (isbf) ((u16*)Cp)[oidx] = f2b(v);
                        else      ((float*)Cp)[oidx] = v;
                    }
                }
            }
        }
    }
}

// ---------------------------------------------------------------------------
// GRU gates GEMM: grid (2, 48), N=6144. Cols [0,3072): X @ Wih^T (i-gates);
// cols [3072,6144): H @ Whh^T (h-gates). A/B select is block-uniform.
// Writes f32 pre-activations to gates[256][6144].
// ---------------------------------------------------------------------------
template <int RAWB>
__global__ __launch_bounds__(256) void k_gemmG(
    const u16* __restrict__ X, const u16* __restrict__ H,
    const void* __restrict__ Wih, const void* __restrict__ Whh, size_t w_eoff,
    float* __restrict__ gates, const int* __restrict__ flagp)
{
    const bool isbf = (*flagp != 0);
    __shared__ short8 As[128 * 5];
    __shared__ short8 Bs[128 * 5];

    const int tid  = threadIdx.x;
    const int lane = tid & 63;
    const int w    = tid >> 6;
    const int wr   = w >> 1, wc = w & 1;
    const int bm   = blockIdx.x * 128;
    const int bn   = blockIdx.y * 128;
    const bool SEL = (bn >= 3072);
    const u16*  Ap = SEL ? H : X;
    const void* Bp = SEL ? Whh : Wih;
    const int   b0 = SEL ? (bn - 3072) : bn;

    const int srow = tid >> 2;
    const int sg   = tid & 3;
    const int m0   = lane & 31;
    const int kq   = lane >> 5;

    f32x16 acc[2][2];
    #pragma unroll
    for (int i = 0; i < 2; ++i)
        #pragma unroll
        for (int j = 0; j < 2; ++j) acc[i][j] = (f32x16)0.0f;

    short8 av[2], bv[2];
    auto LOADG = [&](int kt) {
        const int k0 = kt << 5;
        #pragma unroll
        for (int i = 0; i < 2; ++i) {
            int r = srow + 64 * i;
            av[i] = *(const short8*)(Ap + (size_t)(bm + r) * 1024 + k0 + sg * 8);
            bv[i] = ld8<RAWB>(Bp, w_eoff + (size_t)(b0 + r) * 1024 + k0 + sg * 8, isbf);
        }
    };

    LOADG(0);
    for (int kt = 0; kt < 32; ++kt) {
        __syncthreads();
        #pragma unroll
        for (int i = 0; i < 2; ++i) {
            int r = srow + 64 * i;
            As[r * 5 + (sg ^ (r & 3))] = av[i];
            Bs[r * 5 + (sg ^ (r & 3))] = bv[i];
        }
        __syncthreads();
        if (kt + 1 < 32) LOADG(kt + 1);
        #pragma unroll
        for (int ks = 0; ks < 2; ++ks) {
            const int gk = ks * 2 + kq;
            short8 af[2], bf[2];
            #pragma unroll
            for (int i = 0; i < 2; ++i) {
                int r = wr * 64 + i * 32 + m0;
                af[i] = As[r * 5 + (gk ^ (r & 3))];
            }
            #pragma unroll
            for (int j = 0; j < 2; ++j) {
                int r = wc * 64 + j * 32 + m0;
                bf[j] = Bs[r * 5 + (gk ^ (r & 3))];
            }
            #pragma unroll
            for (int i = 0; i < 2; ++i)
                #pragma unroll
                for (int j = 0; j < 2; ++j)
                    acc[i][j] = __builtin_amdgcn_mfma_f32_32x32x16_bf16(
                        af[i], bf[j], acc[i][j], 0, 0, 0);
        }
    }

    #pragma unroll
    for (int i = 0; i < 2; ++i) {
        #pragma unroll
        for (int j = 0; j < 2; ++j) {
            #pragma unroll
            for (int reg = 0; reg < 16; ++reg) {
                int row = (reg & 3) + 8 * (reg >> 2) + 4 * kq;
                int gr = bm + wr * 64 + i * 32 + row;
                int gc = bn + wc * 64 + j * 32 + m0;
                gates[(size_t)gr * 6144 + gc] = acc[i][j][reg];
            }
        }
    }
}

// ---------------------------------------------------------------------------
// GRU gate combine: one thread per (b, j). Reads 6 f32 pre-activations,
// applies biases + sigmoid/tanh + blend; writes hfl/Hout(+hist).
// Grid 1024 x 256 threads.
// ---------------------------------------------------------------------------
__global__ __launch_bounds__(256) void k_gate(
    const float* __restrict__ gates, const float* __restrict__ biF,
    const float* __restrict__ bhF, float* __restrict__ hfl,
    const u16* __restrict__ Hin, u16* __restrict__ Hout,
    u16* __restrict__ hist, int t)
{
    const int b = blockIdx.x >> 2;
    const int j = ((blockIdx.x & 3) << 8) + threadIdx.x;
    const float* g = gates + (size_t)b * 6144;
    float ir  = g[j]        + biF[j];
    float iz  = g[1024 + j] + biF[1024 + j];
    float in_ = g[2048 + j] + biF[2048 + j];
    float hr  = g[3072 + j] + bhF[j];
    float hz  = g[4096 + j] + bhF[1024 + j];
    float hn  = g[5120 + j] + bhF[2048 + j];
    float r = 1.f / (1.f + expf(-(ir + hr)));
    float z = 1.f / (1.f + expf(-(iz + hz)));
    float n = tanhf(in_ + r * hn);
    size_t hidx = (size_t)b * 1024 + j;
    float hold = hfl ? hfl[hidx] : b2f(Hin[hidx]);
    float hnew = (1.f - z) * n + z * hold;
    if (hfl) hfl[hidx] = hnew;
    u16 h16 = f2b(hnew);
    Hout[hidx] = h16;
    if (hist) hist[(size_t)(t * NB + b) * HH + j] = h16;
}

// ---------------------------------------------------------------------------
// Fallback fused GRU layer (round-5 variant): 256 threads = two 2-wave
// K-groups; 48 KB LDS union. Grid (32, 4) J0-major.
// ---------------------------------------------------------------------------
template <int RAWB>
__global__ __launch_bounds__(256) void k_gruf(
    const u16* __restrict__ X, const u16* __restrict__ Hin,
    const void* __restrict__ Wih, const void* __restrict__ Whh, size_t w_eoff,
    const float* __restrict__ biF, const float* __restrict__ bhF,
    float* __restrict__ hfl, u16* __restrict__ Hout,
    u16* __restrict__ hist, int t, const int* __restrict__ flagp)
{
    const bool isbf = (*flagp != 0);
    __shared__ __align__(16) char smem[49152];

    const int tid  = threadIdx.x;
    const int g    = tid >> 7;
    const int tid2 = tid & 127;
    short8* Xs = (short8*)(smem + g * 20480);
    short8* Hs = (short8*)(smem + g * 20480 + 4096);
    short8* Ws = (short8*)(smem + g * 20480 + 8192);
    float*  Pp = (float*)smem;

    const int lane = tid2 & 63;
    const int w    = tid2 >> 6;
    const int J0   = blockIdx.x * 32;
    const int bm   = blockIdx.y * 64;
    const int m0   = lane & 31;
    const int kq   = lane >> 5;

    f32x16 acc[6];
    #pragma unroll
    for (int q = 0; q < 6; ++q) acc[q] = (f32x16)0.0f;

    const int srr = tid2 >> 2;
    const int sg  = tid2 & 3;

    short8 xv[2], hv[2], wv[6];
    auto LOAD = [&](int kt) {
        const int k0 = kt << 5;
        #pragma unroll
        for (int i = 0; i < 2; ++i) {
            int idx = i * 128 + tid2;
            int row = idx >> 2, gg = idx & 3;
            xv[i] = *(const short8*)(X   + (size_t)(bm + row) * 1024 + k0 + gg * 8);
            hv[i] = *(const short8*)(Hin + (size_t)(bm + row) * 1024 + k0 + gg * 8);
        }
        #pragma unroll
        for (int i = 0; i < 6; ++i) {
            int gate = (i < 3) ? i : i - 3;
            const void* mat = (i < 3) ? Wih : Whh;
            size_t grow = (size_t)(gate * 1024 + J0 + srr);
            wv[i] = ld8<RAWB>(mat, w_eoff + grow * 1024 + k0 + sg * 8, isbf);
        }
    };

    const int kt0 = g * 16;
    LOAD(kt0);
    for (int i = 0; i < 16; ++i) {
        __syncthreads();
        #pragma unroll
        for (int ii = 0; ii < 2; ++ii) {
            int idx = ii * 128 + tid2;
            int row = idx >> 2, gg = idx & 3;
            Xs[row * 4 + (gg ^ (row & 3))] = xv[ii];
            Hs[row * 4 + (gg ^ (row & 3))] = hv[ii];
        }
        #pragma unroll
        for (int ii = 0; ii < 6; ++ii) {
            Ws[(ii * 32 + srr) * 4 + (sg ^ (srr & 3))] = wv[ii];
        }
        __syncthreads();
        if (i < 15) LOAD(kt0 + i + 1);
        #pragma unroll
        for (int ks = 0; ks < 2; ++ks) {
            const int gk = ks * 2 + kq;
            const int r = w * 32 + m0;
            short8 ax = Xs[r * 4 + (gk ^ (r & 3))];
            short8 ah = Hs[r * 4 + (gk ^ (r & 3))];
            short8 bw[6];
            #pragma unroll
            for (int q = 0; q < 6; ++q)
                bw[q] = Ws[(q * 32 + m0) * 4 + (gk ^ (m0 & 3))];
            acc[0] = __builtin_amdgcn_mfma_f32_32x32x16_bf16(ax, bw[0], acc[0], 0, 0, 0);
            acc[1] = __builtin_amdgcn_mfma_f32_32x32x16_bf16(ax, bw[1], acc[1], 0, 0, 0);
            acc[2] = __builtin_amdgcn_mfma_f32_32x32x16_bf16(ax, bw[2], acc[2], 0, 0, 0);
            acc[3] = __builtin_amdgcn_mfma_f32_32x32x16_bf16(ah, bw[3], acc[3], 0, 0, 0);
            acc[4] = __builtin_amdgcn_mfma_f32_32x32x16_bf16(ah, bw[4], acc[4], 0, 0, 0);
            acc[5] = __builtin_amdgcn_mfma_f32_32x32x16_bf16(ah, bw[5], acc[5], 0, 0, 0);
        }
    }

    __syncthreads();
    if (g == 1) {
        #pragma unroll
        for (int q = 0; q < 6; ++q)
            #pragma unroll
            for (int reg = 0; reg < 16; ++reg)
                Pp[(q * 16 + reg) * 128 + tid2] = acc[q][reg];
    }
    __syncthreads();
    if (g == 0) {
        #pragma unroll
        for (int q = 0; q < 6; ++q)
            #pragma unroll
            for (int reg = 0; reg < 16; ++reg)
                acc[q][reg] += Pp[(q * 16 + reg) * 128 + tid2];

        const int jg = J0 + m0;
        const float bir = biF[jg],         bhr = bhF[jg];
        const float biz = biF[1024 + jg],  bhz = bhF[1024 + jg];
        const float bin_ = biF[2048 + jg], bhn = bhF[2048 + jg];
        #pragma unroll
        for (int reg = 0; reg < 16; ++reg) {
            int row = (reg & 3) + 8 * (reg >> 2) + 4 * kq;
            int bb = bm + w * 32 + row;
            float ir  = acc[0][reg] + bir;
            float iz  = acc[1][reg] + biz;
            float in_ = acc[2][reg] + bin_;
            float hr  = acc[3][reg] + bhr;
            float hz  = acc[4][reg] + bhz;
            float hn  = acc[5][reg] + bhn;
            float r = 1.f / (1.f + expf(-(ir + hr)));
            float z = 1.f / (1.f + expf(-(iz + hz)));
            float n = tanhf(in_ + r * hn);
            size_t hidx = (size_t)bb * 1024 + jg;
            float hold = hfl ? hfl[hidx] : b2f(Hin[hidx]);
            float hnew = (1.f - z) * n + z * hold;
            if (hfl) hfl[hidx] = hnew;
            u16 h16 = f2b(hnew);
            Hout[hidx] = h16;
            if (hist) hist[(size_t)(t * NB + bb) * HH + jg] = h16;
        }
    }
}

// ---------------------------------------------------------------------------
// Fused attention + comb step: 1024 threads/block, one block per batch elem.
// ---------------------------------------------------------------------------
__global__ __launch_bounds__(1024) void k_attn(
    const u16* __restrict__ hb1, const u16* __restrict__ attnWB,
    const float* __restrict__ attnBF, const void* __restrict__ enc,
    const u16* __restrict__ encW, const u16* __restrict__ W2t,
    const float* __restrict__ combBF, u16* __restrict__ xc,
    u16* __restrict__ wencG, void* __restrict__ d_out,
    const int* __restrict__ flagp, int t)
{
    const bool isbf = (*flagp != 0);
    __shared__ float sc[S_IN];
    __shared__ float pst[8][1024];
    __shared__ float wencS[1024];
    const int tid  = threadIdx.x;
    const int b    = blockIdx.x;
    const int w    = tid >> 6;
    const int lane = tid & 63;

    short8 h0v = *(const short8*)(hb1 + (size_t)b * HH + lane * 8);
    short8 h1v = *(const short8*)(hb1 + (size_t)b * HH + 512 + lane * 8);
    float hr[16];
    #pragma unroll
    for (int e = 0; e < 8; ++e) {
        hr[e]     = b2f((u16)h0v[e]);
        hr[8 + e] = b2f((u16)h1v[e]);
    }

    #pragma unroll
    for (int i = 0; i < 6; ++i) {
        const int s = w * 6 + i;
        const u16* wr = attnWB + (size_t)s * 2048 + 1024 + (size_t)lane * 8;
        float p = 0.f;
        #pragma unroll
        for (int c = 0; c < 2; ++c) {
            short8 v = *(const short8*)(wr + c * 512);
            #pragma unroll
            for (int e = 0; e < 8; ++e) p += hr[c * 8 + e] * b2f((u16)v[e]);
        }
        #pragma unroll
        for (int d = 32; d > 0; d >>= 1) p += __shfl_xor(p, d, 64);
        if (lane == 0) {
            size_t sidx = (size_t)OFF_ATTN + ((size_t)b * T_OUT + t) * S_IN + s;
            float sx = isbf ? b2f(((const u16*)d_out)[sidx])
                            : ((const float*)d_out)[sidx];
            sc[s] = p + attnBF[s] + sx;
        }
    }
    __syncthreads();

    if (w == 0) {
        float a  = sc[lane];
        float bq = (lane < 32) ? sc[64 + lane] : -3.0e38f;
        float m = fmaxf(a, bq);
        #pragma unroll
        for (int d = 32; d > 0; d >>= 1) m = fmaxf(m, __shfl_xor(m, d, 64));
        float e0 = expf(a - m);
        float e1 = (lane < 32) ? expf(bq - m) : 0.f;
        float ss = e0 + e1;
        #pragma unroll
        for (int d = 32; d > 0; d >>= 1) ss += __shfl_xor(ss, d, 64);
        float inv = 1.f / ss;
        sc[lane] = e0 * inv;
        if (lane < 32) sc[64 + lane] = e1 * inv;
    }
    __syncthreads();

    if (tid < S_IN) {
        float a = sc[tid];
        size_t aidx = (size_t)OFF_ATTN + ((size_t)b * T_OUT + t) * S_IN + tid;
        if (isbf) ((u16*)d_out)[aidx] = f2b(a);
        else      ((float*)d_out)[aidx] = a;
    }

    const int rg = tid >> 7;
    const int hx = (tid & 127) * 8;

    if (encW) {
        float acc[8] = {0.f, 0.f, 0.f, 0.f, 0.f, 0.f, 0.f, 0.f};
        const u16* eb = encW + (size_t)b * S_IN * HH + hx;
        #pragma unroll
        for (int it = 0; it < 12; ++it) {
            const int s = it * 8 + rg;
            const float aw = sc[s];
            short8 v = *(const short8*)(eb + (size_t)s * HH);
            #pragma unroll
            for (int e = 0; e < 8; ++e) acc[e] += aw * b2f((u16)v[e]);
        }
        #pragma unroll
        for (int e = 0; e < 8; ++e) pst[rg][hx + e] = acc[e];
        __syncthreads();
        float s = pst[0][tid];
        #pragma unroll
        for (int r2 = 1; r2 < 8; ++r2) s += pst[r2][tid];
        size_t cidx = ((size_t)b * T_OUT + t) * DD + tid;
        float cx = isbf ? b2f(((const u16*)d_out)[cidx])
                        : ((const float*)d_out)[cidx];
        float v = fmaxf(cx + combBF[tid] + s, 0.f);
        xc[(size_t)b * DD + tid] = f2b(v);
        return;
    }

    float acc[8] = {0.f, 0.f, 0.f, 0.f, 0.f, 0.f, 0.f, 0.f};
    if (isbf) {
        const u16* eb = (const u16*)enc + (size_t)b * S_IN * HH + hx;
        #pragma unroll
        for (int it = 0; it < 12; ++it) {
            const int s = it * 8 + rg;
            const float aw = sc[s];
            short8 v = *(const short8*)(eb + (size_t)s * HH);
            #pragma unroll
            for (int e = 0; e < 8; ++e) acc[e] += aw * b2f((u16)v[e]);
        }
    } else {
        const float* eb = (const float*)enc + (size_t)b * S_IN * HH + hx;
        #pragma unroll
        for (int it = 0; it < 12; ++it) {
            const int s = it * 8 + rg;
            const float aw = sc[s];
            f32x4 v0 = *(const f32x4*)(eb + (size_t)s * HH);
            f32x4 v1 = *(const f32x4*)(eb + (size_t)s * HH + 4);
            acc[0] += aw * v0[0]; acc[1] += aw * v0[1];
            acc[2] += aw * v0[2]; acc[3] += aw * v0[3];
            acc[4] += aw * v1[0]; acc[5] += aw * v1[1];
            acc[6] += aw * v1[2]; acc[7] += aw * v1[3];
        }
    }
    #pragma unroll
    for (int e = 0; e < 8; ++e) pst[rg][hx + e] = acc[e];
    __syncthreads();
    {
        float s = pst[0][tid];
        #pragma unroll
        for (int r2 = 1; r2 < 8; ++r2) s += pst[r2][tid];
        wencS[tid] = s;
    }
    __syncthreads();

    if (W2t) {
        const int dq = tid & 255;
        const int kg = tid >> 8;
        const int d4 = dq * 4;
        float a0 = 0.f, a1 = 0.f, a2 = 0.f, a3 = 0.f;
        const u16* wp = W2t + (size_t)(kg * 256) * 1024 + d4;
        const float* ws = wencS + kg * 256;
        #pragma unroll 8
        for (int k = 0; k < 256; ++k) {
            float wv = ws[k];
            ull m = *(const ull*)(wp + (size_t)k * 1024);
            a0 += wv * b2f((u16)(m));
            a1 += wv * b2f((u16)(m >> 16));
            a2 += wv * b2f((u16)(m >> 32));
            a3 += wv * b2f((u16)(m >> 48));
        }
        float* P2 = &pst[0][0];
        P2[kg * 1024 + d4 + 0] = a0;
        P2[kg * 1024 + d4 + 1] = a1;
        P2[kg * 1024 + d4 + 2] = a2;
        P2[kg * 1024 + d4 + 3] = a3;
        __syncthreads();
        float s2 = P2[tid] + P2[1024 + tid] + P2[2048 + tid] + P2[3072 + tid];
        size_t cidx = ((size_t)b * T_OUT + t) * DD + tid;
        float cx = isbf ? b2f(((const u16*)d_out)[cidx])
                        : ((const float*)d_out)[cidx];
        float v = fmaxf(cx + combBF[tid] + s2, 0.f);
        xc[(size_t)b * DD + tid] = f2b(v);
    } else {
        wencG[(size_t)b * HH + tid] = f2b(wencS[tid]);
    }
}

__global__ __launch_bounds__(256) void k_init(const void* __restrict__ hid,
                                              float* __restrict__ hf,
                                              u16* __restrict__ hb,
                                              const int* __restrict__ flagp)
{
    const int i = blockIdx.x * 256 + threadIdx.x;
    float v = *flagp ? b2f(((const u16*)hid)[i]) : ((const float*)hid)[i];
    if (hf) hf[i] = v;
    hb[i] = f2b(v);
}

__global__ __launch_bounds__(256) void k_hidout(const float* __restrict__ hf,
                                                const u16* __restrict__ hb,
                                                void* __restrict__ d_out,
                                                const int* __restrict__ flagp)
{
    const int i = blockIdx.x * 256 + threadIdx.x;
    float v = hf ? hf[i] : b2f(hb[i]);
    if (*flagp) ((u16*)d_out)[OFF_HID + i] = f2b(v);
    else        ((float*)d_out)[OFF_HID + i] = v;
}

// ---------------------------------------------------------------------------
extern "C" void kernel_launch(void* const* d_in, const int* in_sizes, int n_in,
                              void* d_out, int out_size, void* d_ws, size_t ws_size,
                              hipStream_t stream)
{
    const void* target = d_in[0];
    const void* hidden = d_in[1];
    const void* enc    = d_in[2];
    const void* attnW  = d_in[3];
    const void* attnB  = d_in[4];
    const void* combW  = d_in[5];
    const void* combB  = d_in[6];
    const void* Wih    = d_in[7];
    const void* Whh    = d_in[8];
    const void* bih    = d_in[9];
    const void* bhh    = d_in[10];
    const void* out1W  = d_in[11];
    const void* out1B  = d_in[12];
    const void* out2W  = d_in[13];
    const void* out2B  = d_in[14];

    char* ws = (char*)d_ws;
    size_t off = 0;
    #define WSALLOC(name, type, bytes) type* name = (type*)(ws + off); off += (((size_t)(bytes)) + 255) & ~(size_t)255;
    WSALLOC(flag,   int,   256)
    WSALLOC(xcat,   u16,   256*2048*2)        // wenc fallback buffer
    WSALLOC(xc,     u16,   256*1024*2)
    WSALLOC(hbq,    u16,   2*2*256*1024*2)    // ping-pong x 2 layers
    WSALLOC(Wc,     u16,   1024*1024*2)
    WSALLOC(attnWB, u16,   96*2048*2)
    WSALLOC(attnBF, float, 128*4)
    WSALLOC(combBF, float, 1024*4)
    WSALLOC(bihF,   float, 2*3072*4)
    WSALLOC(bhhF,   float, 2*3072*4)
    WSALLOC(bc,     float, 1024*4)
    WSALLOC(W1t,    u16,   1024*1024*2)
    size_t off_nohf = off;
    WSALLOC(hf,     float, 2*256*1024*4)
    WSALLOC(gates,  float, 256*6144*4)        // 6.3 MB GRU pre-activations
    size_t off_core = off;                    // ~17 MB
    WSALLOC(WihB,   u16,   2*3072*1024*2)     // 12.6 MB
    WSALLOC(WhhB,   u16,   2*3072*1024*2)     // 12.6 MB
    WSALLOC(combW2t,u16,   1024*2048*2)       // 4.2 MB slot
    size_t off_big = off;                     // ~46 MB
    WSALLOC(Hist,   u16,   36*256*1024*2)     // 18.9 MB
    size_t off_hist = off;                    // ~65 MB
    WSALLOC(encW,   u16,   256*96*1024*2)     // 50.3 MB  (enc @ combW_wenc^T)
    size_t off_encw = off;                    // ~115 MB
    #undef WSALLOC
    (void)off_nohf;

    const bool useHf   = (ws_size >= off_core);
    const bool BIG     = (ws_size >= off_big);
    const bool useHist = (ws_size >= off_hist);
    const bool useEncW = (ws_size >= off_encw);
    const bool useGates = useHf;              // gates lives in core region
    if (!useHf) hf = nullptr;

    int hostbf = -1;
    if (in_sizes) {
        long long tb = (long long)in_sizes[0];
        const long long n_t = (long long)NB * T_OUT * DD;
        if (tb == n_t * 2) hostbf = 1;
        else if (tb == n_t * 4) hostbf = 0;
    }
    const bool RAWOK = (hostbf == 1);

    k_detect<<<1, 256, 0, stream>>>((const u32*)target, flag);
    k_init<<<2048, 256, 0, stream>>>(hidden, hf, hbq, flag);

    const u16* attnWx = (const u16*)attnW;
    if (!RAWOK) {
        k_cvt16<<<192, 256, 0, stream>>>(attnW, attnWB, 96*2048/4, flag);
        attnWx = attnWB;
    }
    k_cvtf<<<1, 256, 0, stream>>>(attnB, attnBF, 96, flag);
    k_cvtf<<<4, 256, 0, stream>>>(combB, combBF, 1024, flag);
    k_cvtf<<<24, 256, 0, stream>>>(bih, bihF, 6144, flag);
    k_cvtf<<<24, 256, 0, stream>>>(bhh, bhhF, 6144, flag);
    k_trcvt<<<dim3(16, 16), 256, 0, stream>>>(out1W, W1t, 1024, 0, flag);
    if (BIG && !useEncW) {
        k_trcvt<<<dim3(16, 16), 256, 0, stream>>>(combW, combW2t, 2048, 1024, flag);
    }

    // Wc = out2W @ out1W ; bc = out2W @ b1 + b2
    if (RAWOK) {
        k_gemm<EPI_BF16, 0, 0><<<dim3(8, 8, 1), 256, 0, stream>>>(
            out2W, W1t, Wc, 1024, 1024, 1024, 1024, 1024, nullptr, 0, 1024,
            flag, 0, nullptr);
    } else if (BIG) {
        u16* out2Wb = WihB;
        k_cvt16<<<1024, 256, 0, stream>>>(out2W, out2Wb, 1024*1024/4, flag);
        k_gemm<EPI_BF16, 0, 0><<<dim3(8, 8, 1), 256, 0, stream>>>(
            out2Wb, W1t, Wc, 1024, 1024, 1024, 1024, 1024, nullptr, 0, 1024,
            flag, 0, nullptr);
    } else {
        k_gemm<EPI_BF16, 1, 0><<<dim3(8, 8, 1), 256, 0, stream>>>(
            out2W, W1t, Wc, 1024, 1024, 1024, 1024, 1024, nullptr, 0, 1024,
            flag, 0, nullptr);
    }
    k_bc<<<256, 256, 0, stream>>>(out2W, out1B, out2B, bc, flag);

    const void* WihP = Wih;
    const void* WhhP = Whh;
    bool gru_u16 = RAWOK;
    if (!RAWOK && BIG) {
        k_cvt16<<<6144, 256, 0, stream>>>(Wih, WihB, 2*3072*1024/4, flag);
        k_cvt16<<<6144, 256, 0, stream>>>(Whh, WhhB, 2*3072*1024/4, flag);
        WihP = WihB; WhhP = WhhB; gru_u16 = true;
    }

    // Pre-scan hoists
    k_gemm<EPI_CX, 1, 1><<<dim3(72, 8, 1), 256, 0, stream>>>(
        target, combW, d_out, 1024, 2048, 9216, 1024, 1024, nullptr, 0, 1024,
        flag, 0, nullptr);
    k_gemm<EPI_SCX, 1, 1><<<dim3(72, 1, 1), 256, 0, stream>>>(
        target, attnW, d_out, 1024, 2048, 9216, 96, 1024, nullptr, 0, 96,
        flag, 0, nullptr);
    if (useEncW) {
        k_gemm<EPI_BF16, 1, 1><<<dim3(192, 8, 1), 256, 0, stream>>>(
            enc, combW, encW, 1024, 2048, 24576, 1024, 1024, nullptr, 0, 1024,
            flag, 1024, nullptr);
    }

    const size_t L1 = 3072ull * 1024ull;
    const int BUF = 2 * 256 * 1024;
    for (int t = 0; t < T_OUT; ++t) {
        u16* bi = hbq + (t & 1) * BUF;
        u16* bo = hbq + ((t + 1) & 1) * BUF;
        k_attn<<<256, 1024, 0, stream>>>(bi + 262144, attnWx, attnBF, enc,
                                         useEncW ? encW : nullptr,
                                         (BIG && !useEncW) ? combW2t : nullptr,
                                         combBF, xc, xcat, d_out, flag, t);
        if (!BIG && !useEncW) {
            k_gemm<EPI_COMB2, 0, 1><<<dim3(2, 8, 1), 256, 0, stream>>>(
                xcat, combW, xc, 1024, 2048, 256, 1024, 1024, combBF, t, 1024,
                flag, 1024, d_out);
        }
        if (useGates) {
            // layer 0
            if (gru_u16)
                k_gemmG<0><<<dim3(2, 48), 256, 0, stream>>>(
                    xc, bi, WihP, WhhP, 0, gates, flag);
            else
                k_gemmG<1><<<dim3(2, 48), 256, 0, stream>>>(
                    xc, bi, Wih, Whh, 0, gates, flag);
            k_gate<<<1024, 256, 0, stream>>>(gates, bihF, bhhF, hf, bi, bo,
                                             nullptr, t);
            // layer 1
            if (gru_u16)
                k_gemmG<0><<<dim3(2, 48), 256, 0, stream>>>(
                    bo, bi + 262144, WihP, WhhP, L1, gates, flag);
            else
                k_gemmG<1><<<dim3(2, 48), 256, 0, stream>>>(
                    bo, bi + 262144, Wih, Whh, L1, gates, flag);
            k_gate<<<1024, 256, 0, stream>>>(gates, bihF + 3072, bhhF + 3072,
                                             hf ? hf + 262144 : nullptr,
                                             bi + 262144, bo + 262144,
                                             useHist ? Hist : nullptr, t);
        } else if (gru_u16) {
            k_gruf<0><<<dim3(32, 4), 256, 0, stream>>>(
                xc, bi, WihP, WhhP, 0, bihF, bhhF, hf, bo, nullptr, t, flag);
            k_gruf<0><<<dim3(32, 4), 256, 0, stream>>>(
                bo, bi + 262144, WihP, WhhP, L1, bihF + 3072, bhhF + 3072,
                hf ? hf + 262144 : nullptr, bo + 262144,
                useHist ? Hist : nullptr, t, flag);
        } else {
            k_gruf<1><<<dim3(32, 4), 256, 0, stream>>>(
                xc, bi, Wih, Whh, 0, bihF, bhhF, hf, bo, nullptr, t, flag);
            k_gruf<1><<<dim3(32, 4), 256, 0, stream>>>(
                bo, bi + 262144, Wih, Whh, L1, bihF + 3072, bhhF + 3072,
                hf ? hf + 262144 : nullptr, bo + 262144,
                useHist ? Hist : nullptr, t, flag);
        }
        if (!useHist) {
            k_gemm<EPI_YOUT, 0, 0><<<dim3(2, 8, 1), 256, 0, stream>>>(
                bo + 262144, Wc, d_out, 1024, 1024, 256, 1024, 1024, bc, t, 1024,
                flag, 0, nullptr);
        }
    }

    if (useHist) {
        k_gemm<EPI_YBATCH, 0, 0><<<dim3(72, 8, 1), 256, 0, stream>>>(
            Hist, Wc, d_out, 1024, 1024, 9216, 1024, 1024, bc, 0, 1024,
            flag, 0, nullptr);
    }
    k_hidout<<<2048, 256, 0, stream>>>(hf, hbq, d_out, flag);
}